// Round 2
// baseline (820.575 us; speedup 1.0000x reference)
//
#include <hip/hip_runtime.h>
#include <hip/hip_bf16.h>

#define B_SZ 16384
#define N_SZ 64
#define D_SZ 64
#define H_SZ 128

__device__ __forceinline__ float bf2f(__hip_bfloat16 x) { return __bfloat162float(x); }
// decode packed bf16 pair in a uint32 (little-endian)
__device__ __forceinline__ float bflo(unsigned u) { union { unsigned i; float f; } c; c.i = u << 16;         return c.f; }
__device__ __forceinline__ float bfhi(unsigned u) { union { unsigned i; float f; } c; c.i = u & 0xffff0000u; return c.f; }

__device__ __forceinline__ float wave_reduce_sum(float v) {
    #pragma unroll
    for (int off = 32; off > 0; off >>= 1) v += __shfl_down(v, off, 64);
    return __shfl(v, 0, 64);   // broadcast to all lanes
}

// FMODE 0: bf16 tensors, 1: f32 tensors
template<int FMODE>
__device__ __forceinline__ float LD(const void* p, int i) {
    if constexpr (FMODE == 0) return bf2f(((const __hip_bfloat16*)p)[i]);
    else                      return ((const float*)p)[i];
}

// mask modes: 0 = int32, 1 = int8/bool, 2 = bf16, 3 = f32
__device__ __forceinline__ float mval(const void* p, int i, int mode) {
    if (mode == 0) return ((const int*)p)[i]            ? 1.0f : 0.0f;
    if (mode == 1) return ((const unsigned char*)p)[i]  ? 1.0f : 0.0f;
    if (mode == 2) return ((const unsigned short*)p)[i] ? 1.0f : 0.0f;
    return ((const unsigned int*)p)[i]                  ? 1.0f : 0.0f;
}

// dt_node values are strictly positive: a bf16 buffer never sets the sign bit of
// any 16-bit word; an f32 buffer's low-mantissa words do w.p. 1-2^-32 over 32 words.
__device__ int detect_f32(const void* p) {
    const unsigned short* u = (const unsigned short*)p;
    unsigned any_hi = 0;
    for (int i = 0; i < 64; ++i) any_hi |= (u[i] & 0x8000u);
    return any_hi ? 1 : 0;
}

// 0/1-valued mask: layouts are unambiguous from per-byte-position ORs of 128 head bytes.
// int32: only offset%4==0 bytes nonzero, values<=1.  bool: all offsets 0/1.
// bf16 (1.0=0x3F80): bytes [0x80,0x3F] repeating.  f32 (1.0f): [0,0,0x80,0x3F].
__device__ int detect_mask_mode(const void* p) {
    const unsigned char* u = (const unsigned char*)p;
    unsigned o0 = 0, o1 = 0, o2 = 0, o3 = 0, vmax = 0;
    for (int i = 0; i < 128; i += 4) {
        unsigned a = u[i], b = u[i + 1], c = u[i + 2], d = u[i + 3];
        o0 |= a; o1 |= b; o2 |= c; o3 |= d;
        unsigned m1 = a > b ? a : b, m2 = c > d ? c : d;
        unsigned m = m1 > m2 ? m1 : m2;
        vmax = vmax > m ? vmax : m;
    }
    if ((o1 | o2 | o3) == 0) return 0;   // int32 0/1
    if (vmax <= 1)           return 1;   // bool / int8
    if (o0 > 1)              return 2;   // bf16
    return 3;                            // f32
}

struct Smem {
    float nodef[D_SZ];
    float neigh[N_SZ][D_SZ + 1];   // +1 pad: conflict-free column reads
    float att[N_SZ];
    float wn[N_SZ];
    alignas(16) float comb[4 * D_SZ];
    int modes[2];
};

template<int FMODE>
__device__ __forceinline__ void body(
    Smem& sm,
    const void* dt_node, const void* deg_node, const void* cc_node,
    const void* dt_neigh, const void* deg_neigh, const void* cc_neigh,
    const void* neigh_mask, const void* feature_hist,
    const void* t2v_w, const void* t2v_b, const void* node_w, const void* node_b,
    const void* att_W1, const void* att_W2, const void* att_v,
    const void* weight, void* out, int mmode, int b, int tid)
{
    const int lane = tid & 63;
    const int wv   = tid >> 6;

    // per-lane channel parameters (lane == feature channel d)
    const float w_d  = LD<FMODE>(t2v_w,  lane);
    const float b_d  = LD<FMODE>(t2v_b,  lane);
    const float nw_d = LD<FMODE>(node_w, lane);
    const float nb_d = LD<FMODE>(node_b, lane);

    // ---- node feature (wave 0): t2v(|dt|) + lin(deg) + lin(cc), L2-normalized ----
    if (wv == 0) {
        const float t   = fabsf(LD<FMODE>(dt_node, b));
        const float deg = LD<FMODE>(deg_node, b);
        const float cc  = LD<FMODE>(cc_node, b);
        const float v   = fmaf(t, w_d, b_d);
        float f = (lane == 0 ? v : cosf(v)) + fmaf(deg, nw_d, nb_d) + fmaf(cc, nw_d, nb_d);
        const float ss  = wave_reduce_sum(f * f);
        const float inv = 1.0f / fmaxf(sqrtf(ss), 1e-12f);
        sm.nodef[lane] = f * inv;
    }

    // ---- neighbor features: wave wv handles n in [wv*16, wv*16+16) ----
    #pragma unroll
    for (int i = 0; i < 16; ++i) {
        const int n   = wv * 16 + i;
        const int idx = b * N_SZ + n;
        const float t   = fabsf(LD<FMODE>(dt_neigh, idx));
        const float deg = LD<FMODE>(deg_neigh, idx);
        const float cc  = LD<FMODE>(cc_neigh, idx);
        const float v   = fmaf(t, w_d, b_d);
        float f = (lane == 0 ? v : cosf(v)) + fmaf(deg, nw_d, nb_d) + fmaf(cc, nw_d, nb_d);
        const float ss  = wave_reduce_sum(f * f);
        const float inv = 1.0f / fmaxf(sqrtf(ss), 1e-12f);
        sm.neigh[n][lane] = f * inv;
    }
    __syncthreads();

    // ---- nW1[e] = (node_f @ W1)[e], e = lane (redundant per wave: avoids a barrier) ----
    float nW1 = 0.0f;
    for (int d = 0; d < D_SZ; ++d)
        nW1 = fmaf(sm.nodef[d], LD<FMODE>(att_W1, d * D_SZ + lane), nW1);
    const float ve = LD<FMODE>(att_v, lane);

    // ---- additive attention for this wave's 16 neighbors ----
    {
        float acc[16];
        #pragma unroll
        for (int i = 0; i < 16; ++i) acc[i] = nW1;
        for (int d = 0; d < D_SZ; ++d) {
            const float w2 = LD<FMODE>(att_W2, d * D_SZ + lane);  // coalesced, L1-hot
            #pragma unroll
            for (int i = 0; i < 16; ++i)
                acc[i] = fmaf(sm.neigh[wv * 16 + i][d], w2, acc[i]);  // LDS broadcast
        }
        #pragma unroll
        for (int i = 0; i < 16; ++i) {
            float hp = tanhf(acc[i]) * ve;
            hp = wave_reduce_sum(hp);
            if (lane == 0) sm.att[wv * 16 + i] = hp;
        }
    }
    __syncthreads();

    // ---- score, mask, normalization (wave 0, n = lane) ----
    if (wv == 0) {
        const int idx  = b * N_SZ + lane;
        const float dt = LD<FMODE>(dt_neigh, idx);
        const float ts = 1.0f / fmaf(2.0f, dt, 1.0f);   // Decayer(2,'rev')
        const float lr = ts >= 0.0f ? ts : 0.01f * ts;  // leaky_relu
        const float m  = mval(neigh_mask, idx, mmode);
        const float n_in = fmaxf(wave_reduce_sum(m), 1.0f);
        sm.wn[lane] = m * lr * sm.att[lane] / n_in;
    }
    if (wv >= 2) {                                       // stage feature_hist
        const int j = tid - 128;                         // 0..127
        sm.comb[2 * D_SZ + j] = LD<FMODE>(feature_hist, b * 2 * D_SZ + j);
    }
    __syncthreads();

    // ---- neigh_agg (wave 0, d = lane); node_f staging (wave 1) ----
    if (wv == 0) {
        float agg = 0.0f;
        for (int n = 0; n < N_SZ; ++n)
            agg = fmaf(sm.wn[n], sm.neigh[n][lane], agg);
        sm.comb[D_SZ + lane] = agg;
    } else if (wv == 1) {
        sm.comb[lane] = sm.nodef[lane];
    }
    __syncthreads();

    // ---- final GEMV: out[b][h] = relu(combined . weight[h,:]) ----
    if (tid < H_SZ) {
        const int h = tid;
        const float4* c4 = (const float4*)sm.comb;
        float acc = 0.0f;
        if constexpr (FMODE == 0) {
            const uint4* wrow = (const uint4*)((const __hip_bfloat16*)weight + h * 4 * D_SZ);
            #pragma unroll
            for (int q = 0; q < 32; ++q) {
                const uint4 u   = wrow[q];
                const float4 c0 = c4[2 * q];
                const float4 c1 = c4[2 * q + 1];
                acc = fmaf(bflo(u.x), c0.x, acc); acc = fmaf(bfhi(u.x), c0.y, acc);
                acc = fmaf(bflo(u.y), c0.z, acc); acc = fmaf(bfhi(u.y), c0.w, acc);
                acc = fmaf(bflo(u.z), c1.x, acc); acc = fmaf(bfhi(u.z), c1.y, acc);
                acc = fmaf(bflo(u.w), c1.z, acc); acc = fmaf(bfhi(u.w), c1.w, acc);
            }
            ((__hip_bfloat16*)out)[b * H_SZ + h] = __float2bfloat16(fmaxf(acc, 0.0f));
        } else {
            const float4* wrow = (const float4*)((const float*)weight + h * 4 * D_SZ);
            #pragma unroll
            for (int q = 0; q < 64; ++q) {
                const float4 w4 = wrow[q];
                const float4 cv = c4[q];
                acc = fmaf(w4.x, cv.x, acc); acc = fmaf(w4.y, cv.y, acc);
                acc = fmaf(w4.z, cv.z, acc); acc = fmaf(w4.w, cv.w, acc);
            }
            ((float*)out)[b * H_SZ + h] = fmaxf(acc, 0.0f);
        }
    }
}

__global__ __launch_bounds__(256) void fused_model_kernel(
    const void* dt_node, const void* deg_node, const void* cc_node,
    const void* dt_neigh, const void* deg_neigh, const void* cc_neigh,
    const void* neigh_mask, const void* feature_hist,
    const void* t2v_w, const void* t2v_b, const void* node_w, const void* node_b,
    const void* att_W1, const void* att_W2, const void* att_v,
    const void* weight, void* out)
{
    __shared__ Smem sm;
    const int b   = blockIdx.x;
    const int tid = threadIdx.x;

    // dtype sniffing on head bytes only (in-bounds under every interpretation)
    if (tid == 0) {
        sm.modes[0] = detect_f32(dt_node);
        sm.modes[1] = detect_mask_mode(neigh_mask);
    }
    __syncthreads();
    const int fmode = __builtin_amdgcn_readfirstlane(sm.modes[0]);
    const int mmode = __builtin_amdgcn_readfirstlane(sm.modes[1]);

    if (fmode == 0)
        body<0>(sm, dt_node, deg_node, cc_node, dt_neigh, deg_neigh, cc_neigh,
                neigh_mask, feature_hist, t2v_w, t2v_b, node_w, node_b,
                att_W1, att_W2, att_v, weight, out, mmode, b, tid);
    else
        body<1>(sm, dt_node, deg_node, cc_node, dt_neigh, deg_neigh, cc_neigh,
                neigh_mask, feature_hist, t2v_w, t2v_b, node_w, node_b,
                att_W1, att_W2, att_v, weight, out, mmode, b, tid);
}

extern "C" void kernel_launch(void* const* d_in, const int* in_sizes, int n_in,
                              void* d_out, int out_size, void* d_ws, size_t ws_size,
                              hipStream_t stream) {
    fused_model_kernel<<<B_SZ, 256, 0, stream>>>(
        d_in[0],   // dt_node      [B]
        d_in[1],   // deg_node     [B]
        d_in[2],   // cc_node      [B]
        d_in[3],   // dt_neigh     [B,N]
        d_in[4],   // deg_neigh    [B,N]
        d_in[5],   // cc_neigh     [B,N]
        d_in[6],   // neigh_mask   [B,N]
        d_in[7],   // feature_hist [B,2D]
        d_in[8],   // t2v_w        [D]
        d_in[9],   // t2v_b        [D]
        d_in[10],  // node_w       [D]
        d_in[11],  // node_b       [D]
        d_in[12],  // att_W1       [D,D]
        d_in[13],  // att_W2       [D,D]
        d_in[14],  // att_v        [D]
        d_in[15],  // weight       [H,4D]
        d_out);    // out          [B,H]
}

// Round 3
// 465.670 us; speedup vs baseline: 1.7621x; 1.7621x over previous
//
#include <hip/hip_runtime.h>
#include <hip/hip_bf16.h>

#define B_SZ 16384
#define N_SZ 64
#define D_SZ 64
#define H_SZ 128

#define ARS 72    // A row stride, bf16 elems (64 + 8 pad) = 144 B, 16B-aligned
#define WRS 136   // Wstage row stride, bf16 elems (128 + 8 pad) = 272 B, 16B-aligned

typedef short bf16x8 __attribute__((ext_vector_type(8)));
typedef float f32x4  __attribute__((ext_vector_type(4)));

__device__ __forceinline__ float bflo(unsigned u){union{unsigned i;float f;}c;c.i=u<<16;return c.f;}
__device__ __forceinline__ float bfhi(unsigned u){union{unsigned i;float f;}c;c.i=u&0xffff0000u;return c.f;}
__device__ __forceinline__ float bits2f(unsigned short r){union{unsigned i;float f;}c;c.i=((unsigned)r)<<16;return c.f;}
__device__ __forceinline__ unsigned f2bfbits(float f){
    __hip_bfloat16 h = __float2bfloat16(f);           // RNE
    return (unsigned)__builtin_bit_cast(unsigned short, h);
}
__device__ __forceinline__ float bf2f(__hip_bfloat16 x) { return __bfloat162float(x); }

template<int CTRL>
__device__ __forceinline__ float dpp_add(float v){
    int t = __builtin_amdgcn_mov_dpp(__builtin_bit_cast(int, v), CTRL, 0xf, 0xf, true);
    return v + __builtin_bit_cast(float, t);
}

__device__ __forceinline__ float tanh_fast(float x){
    float e = __expf(2.0f * x);                       // v_exp path
    return 1.0f - __fdividef(2.0f, e + 1.0f);         // exact at +-inf saturation
}

// FMODE 0: bf16 tensors, 1: f32 tensors
template<int FMODE>
__device__ __forceinline__ float LD(const void* p, int i) {
    if constexpr (FMODE == 0) return bf2f(((const __hip_bfloat16*)p)[i]);
    else                      return ((const float*)p)[i];
}

template<int FMODE>
__device__ __forceinline__ void load16(const void* p, int off, float* o) {
    if constexpr (FMODE == 0) {
        const uint4* q = (const uint4*)((const unsigned short*)p + off);
        uint4 a = q[0], b = q[1];
        o[0]=bflo(a.x); o[1]=bfhi(a.x); o[2]=bflo(a.y); o[3]=bfhi(a.y);
        o[4]=bflo(a.z); o[5]=bfhi(a.z); o[6]=bflo(a.w); o[7]=bfhi(a.w);
        o[8]=bflo(b.x); o[9]=bfhi(b.x); o[10]=bflo(b.y); o[11]=bfhi(b.y);
        o[12]=bflo(b.z); o[13]=bfhi(b.z); o[14]=bflo(b.w); o[15]=bfhi(b.w);
    } else {
        const float4* q = (const float4*)((const float*)p + off);
        float4 a=q[0],b=q[1],c=q[2],d=q[3];
        o[0]=a.x;o[1]=a.y;o[2]=a.z;o[3]=a.w; o[4]=b.x;o[5]=b.y;o[6]=b.z;o[7]=b.w;
        o[8]=c.x;o[9]=c.y;o[10]=c.z;o[11]=c.w; o[12]=d.x;o[13]=d.y;o[14]=d.z;o[15]=d.w;
    }
}

// mask modes: 0 = int32, 1 = int8/bool, 2 = bf16, 3 = f32
__device__ __forceinline__ float mval(const void* p, int i, int mode) {
    if (mode == 0) return ((const int*)p)[i]            ? 1.0f : 0.0f;
    if (mode == 1) return ((const unsigned char*)p)[i]  ? 1.0f : 0.0f;
    if (mode == 2) return ((const unsigned short*)p)[i] ? 1.0f : 0.0f;
    return ((const unsigned int*)p)[i]                  ? 1.0f : 0.0f;
}

__device__ int detect_f32(const void* p) {   // dt_node strictly positive: see round-1 note
    const unsigned short* u = (const unsigned short*)p;
    unsigned any_hi = 0;
    for (int i = 0; i < 64; ++i) any_hi |= (u[i] & 0x8000u);
    return any_hi ? 1 : 0;
}

__device__ int detect_mask_mode(const void* p) {
    const unsigned char* u = (const unsigned char*)p;
    unsigned o0 = 0, o1 = 0, o2 = 0, o3 = 0, vmax = 0;
    for (int i = 0; i < 128; i += 4) {
        unsigned a = u[i], b = u[i + 1], c = u[i + 2], d = u[i + 3];
        o0 |= a; o1 |= b; o2 |= c; o3 |= d;
        unsigned m1 = a > b ? a : b, m2 = c > d ? c : d;
        unsigned m = m1 > m2 ? m1 : m2;
        vmax = vmax > m ? vmax : m;
    }
    if ((o1 | o2 | o3) == 0) return 0;
    if (vmax <= 1)           return 1;
    if (o0 > 1)              return 2;
    return 3;
}

struct Smem {
    alignas(16) unsigned short A[65 * ARS];     // rows 0..63 neigh_f (bf16, normalized), row 64 node_f
    alignas(16) unsigned short W[64 * WRS];     // Wstage[e][k]: k<64 -> W1[k][e], k>=64 -> W2[k-64][e]
    float att[N_SZ];
    float wn[N_SZ];
    float aggp[4][D_SZ];
    alignas(16) float comb[4 * D_SZ];           // [node_f | neigh_agg | feature_hist]
    int modes[2];
};

// compute one 16-channel chunk of a feature row; quad-reduce norm over the 4 chunk-threads
template<int FMODE>
__device__ __forceinline__ void feat_row(float t, float dc,
                                         const float* w16, const float* b16_,
                                         const float* nw16, const float* nb16,
                                         int c, unsigned short* dstA, float* dstF) {
    float f[16]; float ss = 0.0f;
    #pragma unroll
    for (int j = 0; j < 16; ++j) {
        float v  = fmaf(t, w16[j], b16_[j]);
        float tv = (c == 0 && j == 0) ? v : __cosf(v);   // channel 0 linear, rest cos
        f[j] = tv + fmaf(dc, nw16[j], 2.0f * nb16[j]);   // lin(deg)+lin(cc) folded
        ss = fmaf(f[j], f[j], ss);
    }
    ss += __shfl_xor(ss, 1, 4);
    ss += __shfl_xor(ss, 2, 4);
    const float inv = 1.0f / fmaxf(sqrtf(ss), 1e-12f);
    unsigned pk[8];
    #pragma unroll
    for (int j = 0; j < 8; ++j)
        pk[j] = f2bfbits(f[2*j] * inv) | (f2bfbits(f[2*j+1] * inv) << 16);
    uint4* dst = (uint4*)dstA;
    dst[0] = make_uint4(pk[0], pk[1], pk[2], pk[3]);
    dst[1] = make_uint4(pk[4], pk[5], pk[6], pk[7]);
    if (dstF) {
        #pragma unroll
        for (int j = 0; j < 16; ++j) dstF[j] = f[j] * inv;
    }
}

template<int FMODE>
__device__ __forceinline__ void body(
    Smem& sm,
    const void* dt_node, const void* deg_node, const void* cc_node,
    const void* dt_neigh, const void* deg_neigh, const void* cc_neigh,
    const void* neigh_mask, const void* feature_hist,
    const void* t2v_w, const void* t2v_b, const void* node_w, const void* node_b,
    const void* att_W1, const void* att_W2, const void* att_v,
    const void* weight, void* out, int mmode, int b, int tid)
{
    const int lane = tid & 63;
    const int wv   = tid >> 6;

    // ---------------- Phase 1: features (thread = neighbor n, 16-d chunk c) ----------------
    {
        const int n  = tid >> 2;
        const int c  = tid & 3;
        const int d0 = c * 16;
        float w16[16], b16_[16], nw16[16], nb16[16];
        load16<FMODE>(t2v_w,  d0, w16);
        load16<FMODE>(t2v_b,  d0, b16_);
        load16<FMODE>(node_w, d0, nw16);
        load16<FMODE>(node_b, d0, nb16);

        const int idx = b * N_SZ + n;
        const float tn  = fabsf(LD<FMODE>(dt_neigh, idx));
        const float dcn = LD<FMODE>(deg_neigh, idx) + LD<FMODE>(cc_neigh, idx);
        feat_row<FMODE>(tn, dcn, w16, b16_, nw16, nb16, c,
                        sm.A + n * ARS + d0, nullptr);

        if (tid < 4) {   // node row -> A row 64 (bf16) and comb[0..63] (f32)
            const float t  = fabsf(LD<FMODE>(dt_node, b));
            const float dc = LD<FMODE>(deg_node, b) + LD<FMODE>(cc_node, b);
            feat_row<FMODE>(t, dc, w16, b16_, nw16, nb16, c,
                            sm.A + 64 * ARS + d0, sm.comb + d0);
        }
    }

    // ---------------- Phase 1b: stage [W1;W2] transposed -> Wstage[e][k] ----------------
    {
        const void* src = (wv < 2) ? att_W1 : att_W2;
        const int k0  = wv * 32;                 // global k row range [k0, k0+32)
        const int kb  = (wv < 2) ? k0 : k0 - 64; // row within src
        #pragma unroll
        for (int kk = 0; kk < 32; kk += 2) {
            float v0 = LD<FMODE>(src, (kb + kk)     * D_SZ + lane);
            float v1 = LD<FMODE>(src, (kb + kk + 1) * D_SZ + lane);
            unsigned pk = f2bfbits(v0) | (f2bfbits(v1) << 16);
            *(unsigned*)(sm.W + lane * WRS + k0 + kk) = pk;
        }
    }
    __syncthreads();

    // ---------------- Phase 2: MFMA  T[n][e] = node@W1[e] + neigh[n]@W2[e]  (K=128) ----------------
    {
        const int m16  = lane & 15;
        const int quad = lane >> 4;
        const unsigned short* Anode = sm.A + 64 * ARS + quad * 8;                // broadcast rows
        const unsigned short* Arow  = sm.A + (wv * 16 + m16) * ARS + quad * 8;   // this wave's neighbors
        bf16x8 a0 = *(const bf16x8*)(Anode);        // k  0..31  (node)
        bf16x8 a1 = *(const bf16x8*)(Anode + 32);   // k 32..63  (node)
        bf16x8 a2 = *(const bf16x8*)(Arow);         // k 64..95  (neigh d 0..31)
        bf16x8 a3 = *(const bf16x8*)(Arow + 32);    // k 96..127 (neigh d 32..63)

        float p[4] = {0.f, 0.f, 0.f, 0.f};
        #pragma unroll
        for (int et = 0; et < 4; ++et) {
            const unsigned short* Wr = sm.W + (et * 16 + m16) * WRS + quad * 8;
            bf16x8 b0 = *(const bf16x8*)(Wr);
            bf16x8 b1 = *(const bf16x8*)(Wr + 32);
            bf16x8 b2 = *(const bf16x8*)(Wr + 64);
            bf16x8 b3 = *(const bf16x8*)(Wr + 96);
            f32x4 acc = {0.f, 0.f, 0.f, 0.f};
            acc = __builtin_amdgcn_mfma_f32_16x16x32_bf16(a0, b0, acc, 0, 0, 0);
            acc = __builtin_amdgcn_mfma_f32_16x16x32_bf16(a1, b1, acc, 0, 0, 0);
            acc = __builtin_amdgcn_mfma_f32_16x16x32_bf16(a2, b2, acc, 0, 0, 0);
            acc = __builtin_amdgcn_mfma_f32_16x16x32_bf16(a3, b3, acc, 0, 0, 0);
            const float ve = LD<FMODE>(att_v, et * 16 + m16);
            #pragma unroll
            for (int r = 0; r < 4; ++r)
                p[r] = fmaf(tanh_fast(acc[r]), ve, p[r]);
        }
        // att[n] = sum over e: DPP reduce across the 16 lanes of each quad (VALU pipe)
        #pragma unroll
        for (int r = 0; r < 4; ++r) {
            float s = p[r];
            s = dpp_add<0xB1>(s);    // quad_perm xor1
            s = dpp_add<0x4E>(s);    // quad_perm xor2
            s = dpp_add<0x124>(s);   // row_ror:4
            s = dpp_add<0x128>(s);   // row_ror:8
            if (m16 == 0) sm.att[wv * 16 + quad * 4 + r] = s;
        }
    }
    __syncthreads();

    // ---------------- Phase 3: scores+wn (wave 0); feature_hist staging (waves 2,3) ----------------
    if (wv == 0) {
        const int idx  = b * N_SZ + lane;
        const float dt = LD<FMODE>(dt_neigh, idx);
        const float ts = 1.0f / fmaf(2.0f, dt, 1.0f);   // Decayer(2,'rev')
        const float lr = ts >= 0.0f ? ts : 0.01f * ts;  // leaky_relu
        const float m  = mval(neigh_mask, idx, mmode);
        float cnt = m;
        #pragma unroll
        for (int off = 32; off > 0; off >>= 1) cnt += __shfl_down(cnt, off, 64);
        cnt = __shfl(cnt, 0, 64);
        sm.wn[lane] = m * lr * sm.att[lane] / fmaxf(cnt, 1.0f);
    } else if (wv >= 2) {
        const int j = tid - 128;                        // 0..127
        sm.comb[2 * D_SZ + j] = LD<FMODE>(feature_hist, b * 2 * D_SZ + j);
    }
    __syncthreads();

    // ---------------- Phase 4: neigh_agg partials (wave wv -> its 16 neighbors) ----------------
    {
        float part = 0.0f;
        #pragma unroll
        for (int i = 0; i < 16; ++i) {
            const int n = wv * 16 + i;
            part = fmaf(sm.wn[n], bits2f(sm.A[n * ARS + lane]), part);
        }
        sm.aggp[wv][lane] = part;
    }
    __syncthreads();
    if (wv == 1)
        sm.comb[D_SZ + lane] = sm.aggp[0][lane] + sm.aggp[1][lane]
                             + sm.aggp[2][lane] + sm.aggp[3][lane];
    __syncthreads();

    // ---------------- Phase 5: GEMV out[h] = relu(comb . weight[h]), split-K over thread pairs ----------------
    {
        const int h  = tid >> 1;
        const int kh = tid & 1;
        const float4* c4 = (const float4*)(sm.comb + kh * 128);
        float acc = 0.0f;
        if constexpr (FMODE == 0) {
            const uint4* wrow = (const uint4*)((const unsigned short*)weight + h * 4 * D_SZ + kh * 128);
            #pragma unroll
            for (int q = 0; q < 16; ++q) {
                const uint4 u   = wrow[q];
                const float4 c0 = c4[2 * q];
                const float4 c1 = c4[2 * q + 1];
                acc = fmaf(bflo(u.x), c0.x, acc); acc = fmaf(bfhi(u.x), c0.y, acc);
                acc = fmaf(bflo(u.y), c0.z, acc); acc = fmaf(bfhi(u.y), c0.w, acc);
                acc = fmaf(bflo(u.z), c1.x, acc); acc = fmaf(bfhi(u.z), c1.y, acc);
                acc = fmaf(bflo(u.w), c1.z, acc); acc = fmaf(bfhi(u.w), c1.w, acc);
            }
        } else {
            const float4* wrow = (const float4*)((const float*)weight + h * 4 * D_SZ + kh * 128);
            #pragma unroll
            for (int q = 0; q < 32; ++q) {
                const float4 w4 = wrow[q];
                const float4 cv = c4[q];
                acc = fmaf(w4.x, cv.x, acc); acc = fmaf(w4.y, cv.y, acc);
                acc = fmaf(w4.z, cv.z, acc); acc = fmaf(w4.w, cv.w, acc);
            }
        }
        acc += __shfl_xor(acc, 1, 64);
        if (kh == 0) {
            if constexpr (FMODE == 0)
                ((__hip_bfloat16*)out)[b * H_SZ + h] = __float2bfloat16(fmaxf(acc, 0.0f));
            else
                ((float*)out)[b * H_SZ + h] = fmaxf(acc, 0.0f);
        }
    }
}

__global__ __launch_bounds__(256) void fused_model_kernel(
    const void* dt_node, const void* deg_node, const void* cc_node,
    const void* dt_neigh, const void* deg_neigh, const void* cc_neigh,
    const void* neigh_mask, const void* feature_hist,
    const void* t2v_w, const void* t2v_b, const void* node_w, const void* node_b,
    const void* att_W1, const void* att_W2, const void* att_v,
    const void* weight, void* out)
{
    __shared__ Smem sm;
    const int b   = blockIdx.x;
    const int tid = threadIdx.x;

    if (tid == 0) {
        sm.modes[0] = detect_f32(dt_node);
        sm.modes[1] = detect_mask_mode(neigh_mask);
    }
    __syncthreads();
    const int fmode = __builtin_amdgcn_readfirstlane(sm.modes[0]);
    const int mmode = __builtin_amdgcn_readfirstlane(sm.modes[1]);

    if (fmode == 0)
        body<0>(sm, dt_node, deg_node, cc_node, dt_neigh, deg_neigh, cc_neigh,
                neigh_mask, feature_hist, t2v_w, t2v_b, node_w, node_b,
                att_W1, att_W2, att_v, weight, out, mmode, b, tid);
    else
        body<1>(sm, dt_node, deg_node, cc_node, dt_neigh, deg_neigh, cc_neigh,
                neigh_mask, feature_hist, t2v_w, t2v_b, node_w, node_b,
                att_W1, att_W2, att_v, weight, out, mmode, b, tid);
}

extern "C" void kernel_launch(void* const* d_in, const int* in_sizes, int n_in,
                              void* d_out, int out_size, void* d_ws, size_t ws_size,
                              hipStream_t stream) {
    fused_model_kernel<<<B_SZ, 256, 0, stream>>>(
        d_in[0], d_in[1], d_in[2], d_in[3], d_in[4], d_in[5], d_in[6], d_in[7],
        d_in[8], d_in[9], d_in[10], d_in[11], d_in[12], d_in[13], d_in[14], d_in[15],
        d_out);
}

// Round 4
// 391.080 us; speedup vs baseline: 2.0982x; 1.1907x over previous
//
#include <hip/hip_runtime.h>
#include <hip/hip_bf16.h>

#define B_SZ 16384
#define N_SZ 64
#define D_SZ 64
#define H_SZ 128
#define R_PB 4              // rows per block
#define ARS 72              // A row stride, bf16 elems (144 B = 9*16 B -> conflict-free b128)
#define CRS 264             // comb row stride, bf16 elems (528 B = 33*16 B)

typedef short bf16x8 __attribute__((ext_vector_type(8)));
typedef float f32x4  __attribute__((ext_vector_type(4)));

__device__ __forceinline__ float bflo(unsigned u){union{unsigned i;float f;}c;c.i=u<<16;return c.f;}
__device__ __forceinline__ float bfhi(unsigned u){union{unsigned i;float f;}c;c.i=u&0xffff0000u;return c.f;}
__device__ __forceinline__ float bits2f(unsigned short r){union{unsigned i;float f;}c;c.i=((unsigned)r)<<16;return c.f;}
__device__ __forceinline__ unsigned f2bfbits(float f){
    __hip_bfloat16 h = __float2bfloat16(f);           // RNE
    return (unsigned)__builtin_bit_cast(unsigned short, h);
}
__device__ __forceinline__ float bf2f(__hip_bfloat16 x) { return __bfloat162float(x); }

template<int CTRL>
__device__ __forceinline__ float dpp_add(float v){
    int t = __builtin_amdgcn_mov_dpp(__builtin_bit_cast(int, v), CTRL, 0xf, 0xf, true);
    return v + __builtin_bit_cast(float, t);
}

__device__ __forceinline__ float tanh_fast(float x){
    float e = __expf(2.0f * x);
    return 1.0f - __fdividef(2.0f, e + 1.0f);         // exact at +-inf saturation
}

// FMODE 0: bf16 tensors, 1: f32 tensors
template<int FMODE>
__device__ __forceinline__ float LD(const void* p, int i) {
    if constexpr (FMODE == 0) return bf2f(((const __hip_bfloat16*)p)[i]);
    else                      return ((const float*)p)[i];
}

template<int FMODE>
__device__ __forceinline__ void load16(const void* p, int off, float* o) {
    if constexpr (FMODE == 0) {
        const uint4* q = (const uint4*)((const unsigned short*)p + off);
        uint4 a = q[0], b = q[1];
        o[0]=bflo(a.x); o[1]=bfhi(a.x); o[2]=bflo(a.y); o[3]=bfhi(a.y);
        o[4]=bflo(a.z); o[5]=bfhi(a.z); o[6]=bflo(a.w); o[7]=bfhi(a.w);
        o[8]=bflo(b.x); o[9]=bfhi(b.x); o[10]=bflo(b.y); o[11]=bfhi(b.y);
        o[12]=bflo(b.z); o[13]=bfhi(b.z); o[14]=bflo(b.w); o[15]=bfhi(b.w);
    } else {
        const float4* q = (const float4*)((const float*)p + off);
        float4 a=q[0],b=q[1],c=q[2],d=q[3];
        o[0]=a.x;o[1]=a.y;o[2]=a.z;o[3]=a.w; o[4]=b.x;o[5]=b.y;o[6]=b.z;o[7]=b.w;
        o[8]=c.x;o[9]=c.y;o[10]=c.z;o[11]=c.w; o[12]=d.x;o[13]=d.y;o[14]=d.z;o[15]=d.w;
    }
}

// mask modes: 0 = int32, 1 = int8/bool, 2 = bf16, 3 = f32
__device__ __forceinline__ float mval(const void* p, int i, int mode) {
    if (mode == 0) return ((const int*)p)[i]            ? 1.0f : 0.0f;
    if (mode == 1) return ((const unsigned char*)p)[i]  ? 1.0f : 0.0f;
    if (mode == 2) return ((const unsigned short*)p)[i] ? 1.0f : 0.0f;
    return ((const unsigned int*)p)[i]                  ? 1.0f : 0.0f;
}

__device__ int detect_f32(const void* p) {   // dt_node strictly positive: bf16 words never set bit15
    const unsigned short* u = (const unsigned short*)p;
    unsigned any_hi = 0;
    for (int i = 0; i < 64; ++i) any_hi |= (u[i] & 0x8000u);
    return any_hi ? 1 : 0;
}

__device__ int detect_mask_mode(const void* p) {
    const unsigned char* u = (const unsigned char*)p;
    unsigned o0 = 0, o1 = 0, o2 = 0, o3 = 0, vmax = 0;
    for (int i = 0; i < 128; i += 4) {
        unsigned a = u[i], b = u[i + 1], c = u[i + 2], d = u[i + 3];
        o0 |= a; o1 |= b; o2 |= c; o3 |= d;
        unsigned m1 = a > b ? a : b, m2 = c > d ? c : d;
        unsigned m = m1 > m2 ? m1 : m2;
        vmax = vmax > m ? vmax : m;
    }
    if ((o1 | o2 | o3) == 0) return 0;
    if (vmax <= 1)           return 1;
    if (o0 > 1)              return 2;
    return 3;
}

struct Smem {
    alignas(16) unsigned short A[R_PB * 65 * ARS];  // [row][n 0..63 | node=64][d] normalized bf16
    alignas(16) unsigned short comb[16 * CRS];      // rows 0..3 valid: [node_f|agg|hist]; 4..15 dummy
    float att[R_PB][N_SZ];
    float wn[R_PB][N_SZ];
    int modes[2];
};

// one 16-channel chunk of a feature row; norm reduced across the 4 chunk-threads (width-4 shfl)
template<int FMODE>
__device__ __forceinline__ void feat_row(float t, float dc,
                                         const float* w16, const float* b16_,
                                         const float* nw16, const float* nb16,
                                         int c, unsigned short* dstA, unsigned short* dstC) {
    float f[16]; float ss = 0.0f;
    #pragma unroll
    for (int j = 0; j < 16; ++j) {
        float v  = fmaf(t, w16[j], b16_[j]);
        float tv = (c == 0 && j == 0) ? v : __cosf(v);   // channel 0 linear, rest cos
        f[j] = tv + fmaf(dc, nw16[j], 2.0f * nb16[j]);   // lin(deg)+lin(cc) folded
        ss = fmaf(f[j], f[j], ss);
    }
    ss += __shfl_xor(ss, 1, 4);
    ss += __shfl_xor(ss, 2, 4);
    const float inv = 1.0f / fmaxf(sqrtf(ss), 1e-12f);
    unsigned pk[8];
    #pragma unroll
    for (int j = 0; j < 8; ++j)
        pk[j] = f2bfbits(f[2*j] * inv) | (f2bfbits(f[2*j+1] * inv) << 16);
    uint4 v0 = make_uint4(pk[0], pk[1], pk[2], pk[3]);
    uint4 v1 = make_uint4(pk[4], pk[5], pk[6], pk[7]);
    ((uint4*)dstA)[0] = v0; ((uint4*)dstA)[1] = v1;
    if (dstC) { ((uint4*)dstC)[0] = v0; ((uint4*)dstC)[1] = v1; }
}

template<int FMODE>
__device__ __forceinline__ void body(
    Smem& sm,
    const void* dt_node, const void* deg_node, const void* cc_node,
    const void* dt_neigh, const void* deg_neigh, const void* cc_neigh,
    const void* neigh_mask, const void* feature_hist,
    const void* t2v_w, const void* t2v_b, const void* node_w, const void* node_b,
    const void* att_W1, const void* att_W2, const void* att_v,
    const void* weight, void* out, int mmode, int b0, int tid)
{
    const int lane = tid & 63;
    const int wv   = tid >> 6;
    const int m16  = lane & 15;
    const int quad = lane >> 4;

    // ---- W fragments (B-operand for S-MFMA) into registers, once per block ----
    // frag(et,ks): lane(m16,quad) holds Wcat[ks*32+quad*8+j][et*16+m16], Wcat=[W1;W2]
    bf16x8 WF[4][4];
    #pragma unroll
    for (int et = 0; et < 4; ++et)
        #pragma unroll
        for (int ks = 0; ks < 4; ++ks) {
            bf16x8 w;
            #pragma unroll
            for (int j = 0; j < 8; ++j) {
                const int i   = ks * 32 + quad * 8 + j;
                const int col = et * 16 + m16;
                if constexpr (FMODE == 0) {
                    const unsigned short* src = (i < 64)
                        ? (const unsigned short*)att_W1 + i * D_SZ
                        : (const unsigned short*)att_W2 + (i - 64) * D_SZ;
                    w[j] = (short)src[col];
                } else {
                    const float* src = (i < 64)
                        ? (const float*)att_W1 + i * D_SZ
                        : (const float*)att_W2 + (i - 64) * D_SZ;
                    w[j] = (short)f2bfbits(src[col]);
                }
            }
            WF[et][ks] = w;
        }

    // ---- Phase 1: features. 1040 tasks = (4 rows x 65 feat-rows) x 4 chunks ----
    #pragma unroll
    for (int it = 0; it < 5; ++it) {
        const int t = tid + it * 256;
        if (t < R_PB * 65 * 4) {
            const int f = t >> 2, c = t & 3, d0 = c * 16;
            float w16[16], b16_[16], nw16[16], nb16[16];
            load16<FMODE>(t2v_w,  d0, w16);
            load16<FMODE>(t2v_b,  d0, b16_);
            load16<FMODE>(node_w, d0, nw16);
            load16<FMODE>(node_b, d0, nb16);
            if (f < R_PB * 64) {
                const int row = f >> 6, n = f & 63;
                const int idx = (b0 + row) * N_SZ + n;
                const float tn  = fabsf(LD<FMODE>(dt_neigh, idx));
                const float dcn = LD<FMODE>(deg_neigh, idx) + LD<FMODE>(cc_neigh, idx);
                feat_row<FMODE>(tn, dcn, w16, b16_, nw16, nb16, c,
                                sm.A + (row * 65 + n) * ARS + d0, nullptr);
            } else {
                const int row = f - R_PB * 64;
                const float tn = fabsf(LD<FMODE>(dt_node, b0 + row));
                const float dc = LD<FMODE>(deg_node, b0 + row) + LD<FMODE>(cc_node, b0 + row);
                feat_row<FMODE>(tn, dc, w16, b16_, nw16, nb16, c,
                                sm.A + (row * 65 + 64) * ARS + d0,
                                sm.comb + row * CRS + d0);
            }
        }
    }
    __syncthreads();

    // ---- Phase 2: S + att for row r = wv (wave-private from here to the GEMV barrier) ----
    {
        const int r = wv;
        const unsigned short* An = sm.A + (r * 65 + 64) * ARS + quad * 8;
        const bf16x8 a0 = *(const bf16x8*)An;          // node k  0..31
        const bf16x8 a1 = *(const bf16x8*)(An + 32);   // node k 32..63
        float ve[4];
        #pragma unroll
        for (int et = 0; et < 4; ++et) ve[et] = LD<FMODE>(att_v, et * 16 + m16);

        #pragma unroll
        for (int mt = 0; mt < 4; ++mt) {
            const unsigned short* Ar = sm.A + (r * 65 + mt * 16 + m16) * ARS + quad * 8;
            const bf16x8 a2 = *(const bf16x8*)Ar;          // neigh k  0..31
            const bf16x8 a3 = *(const bf16x8*)(Ar + 32);   // neigh k 32..63
            float p[4] = {0.f, 0.f, 0.f, 0.f};
            #pragma unroll
            for (int et = 0; et < 4; ++et) {
                f32x4 acc = {0.f, 0.f, 0.f, 0.f};
                acc = __builtin_amdgcn_mfma_f32_16x16x32_bf16(a0, WF[et][0], acc, 0, 0, 0);
                acc = __builtin_amdgcn_mfma_f32_16x16x32_bf16(a1, WF[et][1], acc, 0, 0, 0);
                acc = __builtin_amdgcn_mfma_f32_16x16x32_bf16(a2, WF[et][2], acc, 0, 0, 0);
                acc = __builtin_amdgcn_mfma_f32_16x16x32_bf16(a3, WF[et][3], acc, 0, 0, 0);
                #pragma unroll
                for (int rr = 0; rr < 4; ++rr)
                    p[rr] = fmaf(tanh_fast(acc[rr]), ve[et], p[rr]);
            }
            #pragma unroll
            for (int rr = 0; rr < 4; ++rr) {   // reduce over e (16 lanes) on the VALU/DPP pipe
                float s = p[rr];
                s = dpp_add<0xB1>(s);    // quad_perm xor1
                s = dpp_add<0x4E>(s);    // quad_perm xor2
                s = dpp_add<0x124>(s);   // row_ror:4
                s = dpp_add<0x128>(s);   // row_ror:8
                if (m16 == 0) sm.att[r][mt * 16 + quad * 4 + rr] = s;
            }
        }
    }

    // ---- Phase 3: scores -> wn; feature_hist -> comb (wave-private) ----
    {
        const int r   = wv;
        const int idx = (b0 + r) * N_SZ + lane;
        const float dt = LD<FMODE>(dt_neigh, idx);
        const float ts = 1.0f / fmaf(2.0f, dt, 1.0f);   // Decayer(2,'rev')
        const float lr = ts >= 0.0f ? ts : 0.01f * ts;  // leaky_relu
        const float m  = mval(neigh_mask, idx, mmode);
        float cnt = m;
        #pragma unroll
        for (int off = 32; off > 0; off >>= 1) cnt += __shfl_down(cnt, off, 64);
        cnt = __shfl(cnt, 0, 64);
        sm.wn[r][lane] = m * lr * sm.att[r][lane] / fmaxf(cnt, 1.0f);

        if constexpr (FMODE == 0) {
            const unsigned u = ((const unsigned*)feature_hist)[(b0 + r) * 64 + lane];
            *(unsigned*)(sm.comb + r * CRS + 2 * D_SZ + 2 * lane) = u;
        } else {
            const float* fh = (const float*)feature_hist + (b0 + r) * 2 * D_SZ + 2 * lane;
            *(unsigned*)(sm.comb + r * CRS + 2 * D_SZ + 2 * lane) =
                f2bfbits(fh[0]) | (f2bfbits(fh[1]) << 16);
        }
    }

    // ---- Phase 4: neigh_agg (wave-private; lane = d) ----
    {
        const int r = wv;
        float agg = 0.0f;
        #pragma unroll
        for (int n = 0; n < N_SZ; ++n) {
            const float w = sm.wn[r][n];                                  // LDS broadcast
            agg = fmaf(w, bits2f(sm.A[(r * 65 + n) * ARS + lane]), agg);  // 2-way, free
        }
        sm.comb[r * CRS + D_SZ + lane] = (unsigned short)f2bfbits(agg);
    }
    __syncthreads();

    // ---- Phase 5: GEMV via MFMA. M=16 (rows 0..3 valid), N=128 h, K=256 ----
    {
        bf16x8 AF[8];
        #pragma unroll
        for (int ks = 0; ks < 8; ++ks)
            AF[ks] = *(const bf16x8*)(sm.comb + m16 * CRS + ks * 32 + quad * 8);
        #pragma unroll
        for (int t2 = 0; t2 < 2; ++t2) {
            const int nt = wv * 2 + t2;
            f32x4 c = {0.f, 0.f, 0.f, 0.f};
            #pragma unroll
            for (int ks = 0; ks < 8; ++ks) {
                bf16x8 bw;
                if constexpr (FMODE == 0) {
                    bw = *(const bf16x8*)((const unsigned short*)weight
                            + (nt * 16 + m16) * (4 * D_SZ) + ks * 32 + quad * 8);
                } else {
                    const float* wr = (const float*)weight
                            + (nt * 16 + m16) * (4 * D_SZ) + ks * 32 + quad * 8;
                    #pragma unroll
                    for (int j = 0; j < 8; ++j) bw[j] = (short)f2bfbits(wr[j]);
                }
                c = __builtin_amdgcn_mfma_f32_16x16x32_bf16(AF[ks], bw, c, 0, 0, 0);
            }
            if (quad == 0) {   // C rows 0..3 live in quad 0, reg rr; col = m16
                #pragma unroll
                for (int rr = 0; rr < 4; ++rr) {
                    const float v = fmaxf(c[rr], 0.0f);
                    if constexpr (FMODE == 0)
                        ((__hip_bfloat16*)out)[(b0 + rr) * H_SZ + nt * 16 + m16] = __float2bfloat16(v);
                    else
                        ((float*)out)[(b0 + rr) * H_SZ + nt * 16 + m16] = v;
                }
            }
        }
    }
}

__global__ __launch_bounds__(256, 3) void fused_model_kernel(
    const void* dt_node, const void* deg_node, const void* cc_node,
    const void* dt_neigh, const void* deg_neigh, const void* cc_neigh,
    const void* neigh_mask, const void* feature_hist,
    const void* t2v_w, const void* t2v_b, const void* node_w, const void* node_b,
    const void* att_W1, const void* att_W2, const void* att_v,
    const void* weight, void* out)
{
    __shared__ Smem sm;
    const int b0  = blockIdx.x * R_PB;
    const int tid = threadIdx.x;

    if (tid == 0) {
        sm.modes[0] = detect_f32(dt_node);
        sm.modes[1] = detect_mask_mode(neigh_mask);
    }
    __syncthreads();
    const int fmode = __builtin_amdgcn_readfirstlane(sm.modes[0]);
    const int mmode = __builtin_amdgcn_readfirstlane(sm.modes[1]);

    if (fmode == 0)
        body<0>(sm, dt_node, deg_node, cc_node, dt_neigh, deg_neigh, cc_neigh,
                neigh_mask, feature_hist, t2v_w, t2v_b, node_w, node_b,
                att_W1, att_W2, att_v, weight, out, mmode, b0, tid);
    else
        body<1>(sm, dt_node, deg_node, cc_node, dt_neigh, deg_neigh, cc_neigh,
                neigh_mask, feature_hist, t2v_w, t2v_b, node_w, node_b,
                att_W1, att_W2, att_v, weight, out, mmode, b0, tid);
}

extern "C" void kernel_launch(void* const* d_in, const int* in_sizes, int n_in,
                              void* d_out, int out_size, void* d_ws, size_t ws_size,
                              hipStream_t stream) {
    fused_model_kernel<<<B_SZ / R_PB, 256, 0, stream>>>(
        d_in[0], d_in[1], d_in[2], d_in[3], d_in[4], d_in[5], d_in[6], d_in[7],
        d_in[8], d_in[9], d_in[10], d_in[11], d_in[12], d_in[13], d_in[14], d_in[15],
        d_out);
}

// Round 6
// 243.264 us; speedup vs baseline: 3.3732x; 1.6076x over previous
//
#include <hip/hip_runtime.h>
#include <hip/hip_bf16.h>

#define B_SZ 16384
#define N_SZ 64
#define D_SZ 64
#define H_SZ 128
#define R_PB 4              // rows per block
#define ARS 72              // A row stride, bf16 elems (144 B; 2-way banks on b128 = free)
#define CRS 264             // comb row stride, bf16 elems (528 B = 33*16 B; payload 256 elems!)

typedef short bf16x8 __attribute__((ext_vector_type(8)));
typedef float f32x4  __attribute__((ext_vector_type(4)));

__device__ __forceinline__ float bflo(unsigned u){union{unsigned i;float f;}c;c.i=u<<16;return c.f;}
__device__ __forceinline__ float bfhi(unsigned u){union{unsigned i;float f;}c;c.i=u&0xffff0000u;return c.f;}
__device__ __forceinline__ float bits2f(unsigned short r){union{unsigned i;float f;}c;c.i=((unsigned)r)<<16;return c.f;}
__device__ __forceinline__ unsigned f2bfbits(float f){
    __hip_bfloat16 h = __float2bfloat16(f);           // RNE
    return (unsigned)__builtin_bit_cast(unsigned short, h);
}
__device__ __forceinline__ float bf2f(__hip_bfloat16 x) { return __bfloat162float(x); }

template<int CTRL>
__device__ __forceinline__ float dpp_add(float v){
    int t = __builtin_amdgcn_mov_dpp(__builtin_bit_cast(int, v), CTRL, 0xf, 0xf, true);
    return v + __builtin_bit_cast(float, t);
}

__device__ __forceinline__ float tanh_fast(float x){
    float e = __expf(2.0f * x);
    return 1.0f - __fdividef(2.0f, e + 1.0f);         // exact at +-inf saturation
}

// FMODE 0: bf16 tensors, 1: f32 tensors
template<int FMODE>
__device__ __forceinline__ float LD(const void* p, int i) {
    if constexpr (FMODE == 0) return bf2f(((const __hip_bfloat16*)p)[i]);
    else                      return ((const float*)p)[i];
}

template<int FMODE>
__device__ __forceinline__ void load16(const void* p, int off, float* o) {
    if constexpr (FMODE == 0) {
        const uint4* q = (const uint4*)((const unsigned short*)p + off);
        uint4 a = q[0], b = q[1];
        o[0]=bflo(a.x); o[1]=bfhi(a.x); o[2]=bflo(a.y); o[3]=bfhi(a.y);
        o[4]=bflo(a.z); o[5]=bfhi(a.z); o[6]=bflo(a.w); o[7]=bfhi(a.w);
        o[8]=bflo(b.x); o[9]=bfhi(b.x); o[10]=bflo(b.y); o[11]=bfhi(b.y);
        o[12]=bflo(b.z); o[13]=bfhi(b.z); o[14]=bflo(b.w); o[15]=bfhi(b.w);
    } else {
        const float4* q = (const float4*)((const float*)p + off);
        float4 a=q[0],b=q[1],c=q[2],d=q[3];
        o[0]=a.x;o[1]=a.y;o[2]=a.z;o[3]=a.w; o[4]=b.x;o[5]=b.y;o[6]=b.z;o[7]=b.w;
        o[8]=c.x;o[9]=c.y;o[10]=c.z;o[11]=c.w; o[12]=d.x;o[13]=d.y;o[14]=d.z;o[15]=d.w;
    }
}

// mask modes: 0 = int32, 1 = int8/bool, 2 = bf16, 3 = f32
__device__ __forceinline__ float mval(const void* p, int i, int mode) {
    if (mode == 0) return ((const int*)p)[i]            ? 1.0f : 0.0f;
    if (mode == 1) return ((const unsigned char*)p)[i]  ? 1.0f : 0.0f;
    if (mode == 2) return ((const unsigned short*)p)[i] ? 1.0f : 0.0f;
    return ((const unsigned int*)p)[i]                  ? 1.0f : 0.0f;
}

__device__ int detect_f32(const void* p) {   // dt_node strictly positive: bf16 words never set bit15
    const unsigned short* u = (const unsigned short*)p;
    unsigned any_hi = 0;
    for (int i = 0; i < 64; ++i) any_hi |= (u[i] & 0x8000u);
    return any_hi ? 1 : 0;
}

__device__ int detect_mask_mode(const void* p) {
    const unsigned char* u = (const unsigned char*)p;
    unsigned o0 = 0, o1 = 0, o2 = 0, o3 = 0, vmax = 0;
    for (int i = 0; i < 128; i += 4) {
        unsigned a = u[i], b = u[i + 1], c = u[i + 2], d = u[i + 3];
        o0 |= a; o1 |= b; o2 |= c; o3 |= d;
        unsigned m1 = a > b ? a : b, m2 = c > d ? c : d;
        unsigned m = m1 > m2 ? m1 : m2;
        vmax = vmax > m ? vmax : m;
    }
    if ((o1 | o2 | o3) == 0) return 0;
    if (vmax <= 1)           return 1;
    if (o0 > 1)              return 2;
    return 3;
}

// ---------------- prep: W1/W2 -> MFMA B-fragment layout in d_ws (16 KB) ----------------
// entry t in [0,1024): fi=t>>6 (et=fi>>2, ks=fi&3), lane=t&63 (m16=lane&15, qd=lane>>4)
// holds 8 bf16: Wcat[ks*32+qd*8+j][et*16+m16], j=0..7, Wcat=[W1;W2]
__global__ void prep_kernel(const void* dt_node, const void* att_W1, const void* att_W2,
                            void* ws) {
    const int tid   = threadIdx.x;
    const int fmode = detect_f32(dt_node);
    #pragma unroll
    for (int it = 0; it < 4; ++it) {
        const int t   = tid + it * 256;
        const int fi  = t >> 6, ln = t & 63;
        const int et  = fi >> 2, ks = fi & 3;
        const int m16 = ln & 15, qd = ln >> 4;
        const int col = et * 16 + m16;
        unsigned short s[8];
        #pragma unroll
        for (int j = 0; j < 8; ++j) {
            const int i = ks * 32 + qd * 8 + j;
            if (fmode == 0) {
                s[j] = (i < 64) ? ((const unsigned short*)att_W1)[i * D_SZ + col]
                                : ((const unsigned short*)att_W2)[(i - 64) * D_SZ + col];
            } else {
                const float v = (i < 64) ? ((const float*)att_W1)[i * D_SZ + col]
                                         : ((const float*)att_W2)[(i - 64) * D_SZ + col];
                s[j] = (unsigned short)f2bfbits(v);
            }
        }
        uint4 v = make_uint4(((unsigned)s[0]) | (((unsigned)s[1]) << 16),
                             ((unsigned)s[2]) | (((unsigned)s[3]) << 16),
                             ((unsigned)s[4]) | (((unsigned)s[5]) << 16),
                             ((unsigned)s[6]) | (((unsigned)s[7]) << 16));
        ((uint4*)ws)[t] = v;
    }
}

struct Smem {
    alignas(16) unsigned short A[R_PB * 65 * ARS];  // [row][n 0..63 | node=64][d] normalized bf16
    alignas(16) unsigned short comb[R_PB * CRS];    // [node_f(64) | agg(64) | hist(128)] bf16 + pad
    float att[R_PB][N_SZ];
    float wn[R_PB][N_SZ];
    int modes[2];
};

// one 16-channel chunk of a feature row; norm reduced across the 4 chunk-threads (width-4 shfl)
template<int FMODE>
__device__ __forceinline__ void feat_row(float t, float dc,
                                         const float* w16, const float* b16_,
                                         const float* nw16, const float* nb16,
                                         int c, unsigned short* dstA, unsigned short* dstC) {
    float f[16]; float ss = 0.0f;
    #pragma unroll
    for (int j = 0; j < 16; ++j) {
        float v  = fmaf(t, w16[j], b16_[j]);
        float tv = (c == 0 && j == 0) ? v : __cosf(v);   // channel 0 linear, rest cos
        f[j] = tv + fmaf(dc, nw16[j], 2.0f * nb16[j]);   // lin(deg)+lin(cc) folded
        ss = fmaf(f[j], f[j], ss);
    }
    ss += __shfl_xor(ss, 1, 4);
    ss += __shfl_xor(ss, 2, 4);
    const float inv = 1.0f / fmaxf(sqrtf(ss), 1e-12f);
    unsigned pk[8];
    #pragma unroll
    for (int j = 0; j < 8; ++j)
        pk[j] = f2bfbits(f[2*j] * inv) | (f2bfbits(f[2*j+1] * inv) << 16);
    uint4 v0 = make_uint4(pk[0], pk[1], pk[2], pk[3]);
    uint4 v1 = make_uint4(pk[4], pk[5], pk[6], pk[7]);
    ((uint4*)dstA)[0] = v0; ((uint4*)dstA)[1] = v1;
    if (dstC) { ((uint4*)dstC)[0] = v0; ((uint4*)dstC)[1] = v1; }
}

template<int FMODE, bool USE_WS>
__device__ __forceinline__ void body(
    Smem& sm,
    const void* dt_node, const void* deg_node, const void* cc_node,
    const void* dt_neigh, const void* deg_neigh, const void* cc_neigh,
    const void* neigh_mask, const void* feature_hist,
    const void* t2v_w, const void* t2v_b, const void* node_w, const void* node_b,
    const void* att_W1, const void* att_W2, const void* att_v,
    const void* weight, void* out, const void* ws, int mmode, int b0, int tid)
{
    const int lane = tid & 63;
    const int wv   = tid >> 6;
    const int m16  = lane & 15;
    const int quad = lane >> 4;

    // ---- Phase 1: features. 1040 tasks = (4 rows x 65 feat-rows) x 4 chunks ----
    #pragma unroll
    for (int it = 0; it < 5; ++it) {
        const int t = tid + it * 256;
        if (t < R_PB * 65 * 4) {
            const int f = t >> 2, c = t & 3, d0 = c * 16;
            float w16[16], b16_[16], nw16[16], nb16[16];
            load16<FMODE>(t2v_w,  d0, w16);
            load16<FMODE>(t2v_b,  d0, b16_);
            load16<FMODE>(node_w, d0, nw16);
            load16<FMODE>(node_b, d0, nb16);
            if (f < R_PB * 64) {
                const int row = f >> 6, n = f & 63;
                const int idx = (b0 + row) * N_SZ + n;
                const float tn  = fabsf(LD<FMODE>(dt_neigh, idx));
                const float dcn = LD<FMODE>(deg_neigh, idx) + LD<FMODE>(cc_neigh, idx);
                feat_row<FMODE>(tn, dcn, w16, b16_, nw16, nb16, c,
                                sm.A + (row * 65 + n) * ARS + d0, nullptr);
            } else {
                const int row = f - R_PB * 64;
                const float tn = fabsf(LD<FMODE>(dt_node, b0 + row));
                const float dc = LD<FMODE>(deg_node, b0 + row) + LD<FMODE>(cc_node, b0 + row);
                feat_row<FMODE>(tn, dc, w16, b16_, nw16, nb16, c,
                                sm.A + (row * 65 + 64) * ARS + d0,
                                sm.comb + row * CRS + d0);
            }
        }
    }
    __syncthreads();

    // ---- Phase 2: S + att for row r = wv ----
    // S[m][e] = node@W1[e] (same for all m -> computed once per e-tile) + neigh[m]@W2[e]
    {
        const int r = wv;
        const unsigned short* An = sm.A + (r * 65 + 64) * ARS + quad * 8;
        const bf16x8 a0 = *(const bf16x8*)An;          // node k  0..31
        const bf16x8 a1 = *(const bf16x8*)(An + 32);   // node k 32..63
        const bf16x8* wfrag = (const bf16x8*)ws;

        f32x4  accN[4];      // node@W1 per e-tile (rows identical)
        bf16x8 w2f[4], w3f[4];
        float  ve[4];
        #pragma unroll
        for (int et = 0; et < 4; ++et) {
            bf16x8 w0, w1;
            if constexpr (USE_WS) {
                w0      = wfrag[(et * 4 + 0) * 64 + lane];
                w1      = wfrag[(et * 4 + 1) * 64 + lane];
                w2f[et] = wfrag[(et * 4 + 2) * 64 + lane];
                w3f[et] = wfrag[(et * 4 + 3) * 64 + lane];
            } else {
                const int col = et * 16 + m16;
                #pragma unroll
                for (int j = 0; j < 8; ++j) {
                    const int k0 = quad * 8 + j;
                    if constexpr (FMODE == 0) {
                        w0[j]      = (short)((const unsigned short*)att_W1)[k0 * D_SZ + col];
                        w1[j]      = (short)((const unsigned short*)att_W1)[(k0 + 32) * D_SZ + col];
                        w2f[et][j] = (short)((const unsigned short*)att_W2)[k0 * D_SZ + col];
                        w3f[et][j] = (short)((const unsigned short*)att_W2)[(k0 + 32) * D_SZ + col];
                    } else {
                        w0[j]      = (short)f2bfbits(((const float*)att_W1)[k0 * D_SZ + col]);
                        w1[j]      = (short)f2bfbits(((const float*)att_W1)[(k0 + 32) * D_SZ + col]);
                        w2f[et][j] = (short)f2bfbits(((const float*)att_W2)[k0 * D_SZ + col]);
                        w3f[et][j] = (short)f2bfbits(((const float*)att_W2)[(k0 + 32) * D_SZ + col]);
                    }
                }
            }
            f32x4 z = {0.f, 0.f, 0.f, 0.f};
            z = __builtin_amdgcn_mfma_f32_16x16x32_bf16(a0, w0, z, 0, 0, 0);
            z = __builtin_amdgcn_mfma_f32_16x16x32_bf16(a1, w1, z, 0, 0, 0);
            accN[et] = z;
            ve[et]   = LD<FMODE>(att_v, et * 16 + m16);
        }

        #pragma unroll
        for (int mt = 0; mt < 4; ++mt) {
            const unsigned short* Ar = sm.A + (r * 65 + mt * 16 + m16) * ARS + quad * 8;
            const bf16x8 a2 = *(const bf16x8*)Ar;          // neigh k  0..31
            const bf16x8 a3 = *(const bf16x8*)(Ar + 32);   // neigh k 32..63
            float p0 = 0.f, p1 = 0.f, p2 = 0.f, p3 = 0.f;
            #pragma unroll
            for (int et = 0; et < 4; ++et) {
                f32x4 acc = __builtin_amdgcn_mfma_f32_16x16x32_bf16(a2, w2f[et], accN[et], 0, 0, 0);
                acc       = __builtin_amdgcn_mfma_f32_16x16x32_bf16(a3, w3f[et], acc,      0, 0, 0);
                p0 = fmaf(tanh_fast(acc[0]), ve[et], p0);
                p1 = fmaf(tanh_fast(acc[1]), ve[et], p1);
                p2 = fmaf(tanh_fast(acc[2]), ve[et], p2);
                p3 = fmaf(tanh_fast(acc[3]), ve[et], p3);
            }
            p0 = dpp_add<0xB1>(p0); p0 = dpp_add<0x4E>(p0); p0 = dpp_add<0x124>(p0); p0 = dpp_add<0x128>(p0);
            p1 = dpp_add<0xB1>(p1); p1 = dpp_add<0x4E>(p1); p1 = dpp_add<0x124>(p1); p1 = dpp_add<0x128>(p1);
            p2 = dpp_add<0xB1>(p2); p2 = dpp_add<0x4E>(p2); p2 = dpp_add<0x124>(p2); p2 = dpp_add<0x128>(p2);
            p3 = dpp_add<0xB1>(p3); p3 = dpp_add<0x4E>(p3); p3 = dpp_add<0x124>(p3); p3 = dpp_add<0x128>(p3);
            if (m16 == 0) {
                sm.att[r][mt * 16 + quad * 4 + 0] = p0;
                sm.att[r][mt * 16 + quad * 4 + 1] = p1;
                sm.att[r][mt * 16 + quad * 4 + 2] = p2;
                sm.att[r][mt * 16 + quad * 4 + 3] = p3;
            }
        }
    }

    // ---- Phase 3: scores -> wn; feature_hist -> comb (wave-private) ----
    {
        const int r   = wv;
        const int idx = (b0 + r) * N_SZ + lane;
        const float dt = LD<FMODE>(dt_neigh, idx);
        const float ts = 1.0f / fmaf(2.0f, dt, 1.0f);   // Decayer(2,'rev')
        const float lr = ts >= 0.0f ? ts : 0.01f * ts;  // leaky_relu
        const float m  = mval(neigh_mask, idx, mmode);
        float cnt = m;
        #pragma unroll
        for (int off = 32; off > 0; off >>= 1) cnt += __shfl_down(cnt, off, 64);
        cnt = __shfl(cnt, 0, 64);
        sm.wn[r][lane] = m * lr * sm.att[r][lane] / fmaxf(cnt, 1.0f);

        if constexpr (FMODE == 0) {
            const unsigned u = ((const unsigned*)feature_hist)[(b0 + r) * 64 + lane];
            *(unsigned*)(sm.comb + r * CRS + 2 * D_SZ + 2 * lane) = u;
        } else {
            const float* fh = (const float*)feature_hist + (b0 + r) * 2 * D_SZ + 2 * lane;
            *(unsigned*)(sm.comb + r * CRS + 2 * D_SZ + 2 * lane) =
                f2bfbits(fh[0]) | (f2bfbits(fh[1]) << 16);
        }
    }

    // ---- Phase 4: neigh_agg (wave-private; lane = d) ----
    {
        const int r = wv;
        float agg = 0.0f;
        #pragma unroll
        for (int n = 0; n < N_SZ; ++n) {
            const float w = sm.wn[r][n];                                  // LDS broadcast
            agg = fmaf(w, bits2f(sm.A[(r * 65 + n) * ARS + lane]), agg);  // 2-way, free
        }
        sm.comb[r * CRS + D_SZ + lane] = (unsigned short)f2bfbits(agg);
    }
    __syncthreads();

    // ---- Phase 5: GEMV via MFMA. A rows = comb[m16&3] (duplicated), N=128 h, K=256 ----
    {
        #pragma unroll
        for (int t2 = 0; t2 < 2; ++t2) {
            const int nt = wv * 2 + t2;
            f32x4 c = {0.f, 0.f, 0.f, 0.f};
            #pragma unroll
            for (int ks = 0; ks < 8; ++ks) {
                const bf16x8 af = *(const bf16x8*)(sm.comb + (m16 & 3) * CRS + ks * 32 + quad * 8);
                bf16x8 bw;
                if constexpr (FMODE == 0) {
                    bw = *(const bf16x8*)((const unsigned short*)weight
                            + (nt * 16 + m16) * (4 * D_SZ) + ks * 32 + quad * 8);
                } else {
                    const float* wr = (const float*)weight
                            + (nt * 16 + m16) * (4 * D_SZ) + ks * 32 + quad * 8;
                    #pragma unroll
                    for (int j = 0; j < 8; ++j) bw[j] = (short)f2bfbits(wr[j]);
                }
                c = __builtin_amdgcn_mfma_f32_16x16x32_bf16(af, bw, c, 0, 0, 0);
            }
            if (quad == 0) {   // C rows 0..3 = quad 0, regs 0..3; col = m16
                #pragma unroll
                for (int rr = 0; rr < 4; ++rr) {
                    const float v = fmaxf(c[rr], 0.0f);
                    if constexpr (FMODE == 0)
                        ((__hip_bfloat16*)out)[(b0 + rr) * H_SZ + nt * 16 + m16] = __float2bfloat16(v);
                    else
                        ((float*)out)[(b0 + rr) * H_SZ + nt * 16 + m16] = v;
                }
            }
        }
    }
}

template<bool USE_WS>
__global__ __launch_bounds__(256, 3) void fused_model_kernel(
    const void* dt_node, const void* deg_node, const void* cc_node,
    const void* dt_neigh, const void* deg_neigh, const void* cc_neigh,
    const void* neigh_mask, const void* feature_hist,
    const void* t2v_w, const void* t2v_b, const void* node_w, const void* node_b,
    const void* att_W1, const void* att_W2, const void* att_v,
    const void* weight, void* out, const void* ws)
{
    __shared__ Smem sm;
    const int b0  = blockIdx.x * R_PB;
    const int tid = threadIdx.x;

    if (tid == 0) {
        sm.modes[0] = detect_f32(dt_node);
        sm.modes[1] = detect_mask_mode(neigh_mask);
    }
    __syncthreads();
    const int fmode = __builtin_amdgcn_readfirstlane(sm.modes[0]);
    const int mmode = __builtin_amdgcn_readfirstlane(sm.modes[1]);

    if (fmode == 0)
        body<0, USE_WS>(sm, dt_node, deg_node, cc_node, dt_neigh, deg_neigh, cc_neigh,
                        neigh_mask, feature_hist, t2v_w, t2v_b, node_w, node_b,
                        att_W1, att_W2, att_v, weight, out, ws, mmode, b0, tid);
    else
        body<1, USE_WS>(sm, dt_node, deg_node, cc_node, dt_neigh, deg_neigh, cc_neigh,
                        neigh_mask, feature_hist, t2v_w, t2v_b, node_w, node_b,
                        att_W1, att_W2, att_v, weight, out, ws, mmode, b0, tid);
}

extern "C" void kernel_launch(void* const* d_in, const int* in_sizes, int n_in,
                              void* d_out, int out_size, void* d_ws, size_t ws_size,
                              hipStream_t stream) {
    const bool use_ws = (ws_size >= 16384) && (d_ws != nullptr);
    if (use_ws) {
        prep_kernel<<<1, 256, 0, stream>>>(d_in[0], d_in[12], d_in[13], d_ws);
        fused_model_kernel<true><<<B_SZ / R_PB, 256, 0, stream>>>(
            d_in[0], d_in[1], d_in[2], d_in[3], d_in[4], d_in[5], d_in[6], d_in[7],
            d_in[8], d_in[9], d_in[10], d_in[11], d_in[12], d_in[13], d_in[14], d_in[15],
            d_out, d_ws);
    } else {
        fused_model_kernel<false><<<B_SZ / R_PB, 256, 0, stream>>>(
            d_in[0], d_in[1], d_in[2], d_in[3], d_in[4], d_in[5], d_in[6], d_in[7],
            d_in[8], d_in[9], d_in[10], d_in[11], d_in[12], d_in[13], d_in[14], d_in[15],
            d_out, d_ws);
    }
}

// Round 8
// 218.509 us; speedup vs baseline: 3.7553x; 1.1133x over previous
//
#include <hip/hip_runtime.h>
#include <hip/hip_bf16.h>

#define B_SZ 16384
#define N_SZ 64
#define D_SZ 64
#define H_SZ 128
#define R_PB 4              // rows per block
#define ARS 68              // A row stride, bf16 elems (136 B; <=2-way banks on b128)
#define CRS 264             // comb row stride, bf16 elems (528 B; payload 256 elems)

typedef short bf16x8 __attribute__((ext_vector_type(8)));
typedef float f32x4  __attribute__((ext_vector_type(4)));

__device__ __forceinline__ float bflo(unsigned u){union{unsigned i;float f;}c;c.i=u<<16;return c.f;}
__device__ __forceinline__ float bfhi(unsigned u){union{unsigned i;float f;}c;c.i=u&0xffff0000u;return c.f;}
__device__ __forceinline__ float bits2f(unsigned short r){union{unsigned i;float f;}c;c.i=((unsigned)r)<<16;return c.f;}
__device__ __forceinline__ unsigned f2bfbits(float f){
    __hip_bfloat16 h = __float2bfloat16(f);           // RNE
    unsigned short u;
    __builtin_memcpy(&u, &h, 2);
    return (unsigned)u;
}
__device__ __forceinline__ unsigned pack2bf(float a, float b){   // v_cvt_pk_bf16_f32
    __hip_bfloat162 h = __float22bfloat162_rn(make_float2(a, b));
    unsigned r;
    __builtin_memcpy(&r, &h, 4);
    return r;
}
__device__ __forceinline__ float bf2f(__hip_bfloat16 x) { return __bfloat162float(x); }

template<int CTRL>
__device__ __forceinline__ float dpp_add(float v){
    int t = __builtin_amdgcn_mov_dpp(__builtin_bit_cast(int, v), CTRL, 0xf, 0xf, true);
    return v + __builtin_bit_cast(float, t);
}

__device__ __forceinline__ float tanh_fast(float x){
    float e = __expf(2.0f * x);
    return 1.0f - __fdividef(2.0f, e + 1.0f);         // exact at +-inf saturation
}

// FMODE 0: bf16 tensors, 1: f32 tensors
template<int FMODE>
__device__ __forceinline__ float LD(const void* p, int i) {
    if constexpr (FMODE == 0) return bf2f(((const __hip_bfloat16*)p)[i]);
    else                      return ((const float*)p)[i];
}

template<int FMODE>
__device__ __forceinline__ void load16(const void* p, int off, float* o) {
    if constexpr (FMODE == 0) {
        const uint4* q = (const uint4*)((const unsigned short*)p + off);
        uint4 a = q[0], b = q[1];
        o[0]=bflo(a.x); o[1]=bfhi(a.x); o[2]=bflo(a.y); o[3]=bfhi(a.y);
        o[4]=bflo(a.z); o[5]=bfhi(a.z); o[6]=bflo(a.w); o[7]=bfhi(a.w);
        o[8]=bflo(b.x); o[9]=bfhi(b.x); o[10]=bflo(b.y); o[11]=bfhi(b.y);
        o[12]=bflo(b.z); o[13]=bfhi(b.z); o[14]=bflo(b.w); o[15]=bfhi(b.w);
    } else {
        const float4* q = (const float4*)((const float*)p + off);
        float4 a=q[0],b=q[1],c=q[2],d=q[3];
        o[0]=a.x;o[1]=a.y;o[2]=a.z;o[3]=a.w; o[4]=b.x;o[5]=b.y;o[6]=b.z;o[7]=b.w;
        o[8]=c.x;o[9]=c.y;o[10]=c.z;o[11]=c.w; o[12]=d.x;o[13]=d.y;o[14]=d.z;o[15]=d.w;
    }
}

// mask modes: 0 = int32, 1 = int8/bool, 2 = bf16, 3 = f32
__device__ __forceinline__ float mval(const void* p, int i, int mode) {
    if (mode == 0) return ((const int*)p)[i]            ? 1.0f : 0.0f;
    if (mode == 1) return ((const unsigned char*)p)[i]  ? 1.0f : 0.0f;
    if (mode == 2) return ((const unsigned short*)p)[i] ? 1.0f : 0.0f;
    return ((const unsigned int*)p)[i]                  ? 1.0f : 0.0f;
}

// dt_node strictly positive: bf16 words never set bit15; f32 low-mantissa words do (w.p. 1-2^-32)
__device__ __forceinline__ int detect_f32(const void* p) {
    const uint4* q = (const uint4*)p;
    unsigned o = 0;
    #pragma unroll
    for (int i = 0; i < 8; ++i) { uint4 v = q[i]; o |= v.x | v.y | v.z | v.w; }
    return (o & 0x80008000u) ? 1 : 0;
}

// 0/1-valued mask, 128 head bytes: int32 -> only byte0 of each dword nonzero;
// bool -> all bytes <=1; bf16(1.0=0x3F80) -> lo byte 0x80; f32(1.0f) -> lo byte 0
__device__ __forceinline__ int detect_mask_mode(const void* p) {
    const uint4* q = (const uint4*)p;
    unsigned oa = 0, ofe = 0;
    #pragma unroll
    for (int i = 0; i < 8; ++i) {
        uint4 v = q[i];
        unsigned w = v.x | v.y | v.z | v.w;
        oa  |= w;
        ofe |= (v.x & 0xFEFEFEFEu) | (v.y & 0xFEFEFEFEu) | (v.z & 0xFEFEFEFEu) | (v.w & 0xFEFEFEFEu);
    }
    if ((oa & 0xFFFFFF00u) == 0) return 0;   // int32 0/1
    if (ofe == 0)                return 1;   // bool/int8
    if (oa & 0x000000FEu)        return 2;   // bf16
    return 3;                                // f32
}

// ---------------- prep: W1/W2 -> MFMA B-fragment layout in d_ws (16 KB), grid=4 ----------------
// entry t in [0,1024): fi=t>>6 (et=fi>>2, ks=fi&3), lane=t&63 (m16=lane&15, qd=lane>>4)
// holds 8 bf16: Wcat[ks*32+qd*8+j][et*16+m16], Wcat=[W1;W2]
__global__ void prep_kernel(const void* dt_node, const void* att_W1, const void* att_W2,
                            void* ws) {
    const int t     = blockIdx.x * 256 + threadIdx.x;
    const int fmode = detect_f32(dt_node);
    const int fi  = t >> 6, ln = t & 63;
    const int et  = fi >> 2, ks = fi & 3;
    const int m16 = ln & 15, qd = ln >> 4;
    const int col = et * 16 + m16;
    unsigned short s[8];
    #pragma unroll
    for (int j = 0; j < 8; ++j) {
        const int i = ks * 32 + qd * 8 + j;
        if (fmode == 0) {
            s[j] = (i < 64) ? ((const unsigned short*)att_W1)[i * D_SZ + col]
                            : ((const unsigned short*)att_W2)[(i - 64) * D_SZ + col];
        } else {
            const float v = (i < 64) ? ((const float*)att_W1)[i * D_SZ + col]
                                     : ((const float*)att_W2)[(i - 64) * D_SZ + col];
            s[j] = (unsigned short)f2bfbits(v);
        }
    }
    ((uint4*)ws)[t] = make_uint4(((unsigned)s[0]) | (((unsigned)s[1]) << 16),
                                 ((unsigned)s[2]) | (((unsigned)s[3]) << 16),
                                 ((unsigned)s[4]) | (((unsigned)s[5]) << 16),
                                 ((unsigned)s[6]) | (((unsigned)s[7]) << 16));
}

struct Smem {
    alignas(16) unsigned short A[R_PB * 65 * ARS];  // [row][n 0..63 | node=64][d] normalized bf16
    alignas(16) unsigned short comb[R_PB * CRS];    // [node_f(64) | agg(64) | hist(128)] bf16 + pad
    float att[R_PB][N_SZ];
    float wn[R_PB][N_SZ];
};

// one 16-channel chunk of a feature row; norm reduced across the 4 chunk-threads (width-4 shfl)
// nb16 must arrive PRE-DOUBLED (2*node_b)
template<int FMODE>
__device__ __forceinline__ void feat_row(float t, float dc,
                                         const float* w16, const float* b16_,
                                         const float* nw16, const float* nb16,
                                         int c, unsigned short* dstA, unsigned short* dstC) {
    float f[16]; float ss = 0.0f;
    #pragma unroll
    for (int j = 0; j < 16; ++j) {
        float v  = fmaf(t, w16[j], b16_[j]);
        float tv = (c == 0 && j == 0) ? v : __cosf(v);   // channel 0 linear, rest cos
        f[j] = tv + fmaf(dc, nw16[j], nb16[j]);          // lin(deg)+lin(cc), bias pre-doubled
        ss = fmaf(f[j], f[j], ss);
    }
    ss += __shfl_xor(ss, 1, 4);
    ss += __shfl_xor(ss, 2, 4);
    const float inv = 1.0f / fmaxf(sqrtf(ss), 1e-12f);
    unsigned pk[8];
    #pragma unroll
    for (int j = 0; j < 8; ++j)
        pk[j] = pack2bf(f[2*j] * inv, f[2*j+1] * inv);    // v_cvt_pk_bf16_f32
    uint4 v0 = make_uint4(pk[0], pk[1], pk[2], pk[3]);
    uint4 v1 = make_uint4(pk[4], pk[5], pk[6], pk[7]);
    ((uint4*)dstA)[0] = v0; ((uint4*)dstA)[1] = v1;
    if (dstC) { ((uint4*)dstC)[0] = v0; ((uint4*)dstC)[1] = v1; }
}

template<int FMODE, bool USE_WS>
__device__ __forceinline__ void body(
    Smem& sm,
    const void* dt_node, const void* deg_node, const void* cc_node,
    const void* dt_neigh, const void* deg_neigh, const void* cc_neigh,
    const void* neigh_mask, const void* feature_hist,
    const void* t2v_w, const void* t2v_b, const void* node_w, const void* node_b,
    const void* att_W1, const void* att_W2, const void* att_v,
    const void* weight, void* out, const void* ws, int mmode, int b0, int tid)
{
    const int lane = tid & 63;
    const int wv   = tid >> 6;
    const int m16  = lane & 15;
    const int quad = lane >> 4;

    // ---- Phase 1: features. 1040 tasks = (4 rows x 65 feat-rows) x 4 chunks ----
    {
        const int c = tid & 3, d0 = c * 16;               // chunk invariant across iterations
        float w16[16], b16_[16], nw16[16], nb16[16];
        load16<FMODE>(t2v_w,  d0, w16);
        load16<FMODE>(t2v_b,  d0, b16_);
        load16<FMODE>(node_w, d0, nw16);
        load16<FMODE>(node_b, d0, nb16);
        #pragma unroll
        for (int j = 0; j < 16; ++j) nb16[j] *= 2.0f;     // deg-bias + cc-bias folded

        #pragma unroll
        for (int it = 0; it < 5; ++it) {
            const int t = tid + it * 256;
            if (t < R_PB * 65 * 4) {
                const int f = t >> 2;
                if (f < R_PB * 64) {
                    const int row = f >> 6, n = f & 63;
                    const int idx = (b0 + row) * N_SZ + n;
                    const float tn  = fabsf(LD<FMODE>(dt_neigh, idx));
                    const float dcn = LD<FMODE>(deg_neigh, idx) + LD<FMODE>(cc_neigh, idx);
                    feat_row<FMODE>(tn, dcn, w16, b16_, nw16, nb16, c,
                                    sm.A + (row * 65 + n) * ARS + d0, nullptr);
                } else {
                    const int row = f - R_PB * 64;
                    const float tn = fabsf(LD<FMODE>(dt_node, b0 + row));
                    const float dc = LD<FMODE>(deg_node, b0 + row) + LD<FMODE>(cc_node, b0 + row);
                    feat_row<FMODE>(tn, dc, w16, b16_, nw16, nb16, c,
                                    sm.A + (row * 65 + 64) * ARS + d0,
                                    sm.comb + row * CRS + d0);
                }
            }
        }
    }
    __syncthreads();

    // ---- Phase 2: S + att for row r = wv ----
    // S[m][e] = node@W1[e] (identical for all m -> once per e-tile) + neigh[m]@W2[e]
    {
        const int r = wv;
        const unsigned short* An = sm.A + (r * 65 + 64) * ARS + quad * 8;
        const bf16x8 a0 = *(const bf16x8*)An;          // node k  0..31
        const bf16x8 a1 = *(const bf16x8*)(An + 32);   // node k 32..63
        const bf16x8* wfrag = (const bf16x8*)ws;

        f32x4  accN[4];
        bf16x8 w2f[4], w3f[4];
        float  ve[4];
        #pragma unroll
        for (int et = 0; et < 4; ++et) {
            bf16x8 w0, w1;
            if constexpr (USE_WS) {
                w0      = wfrag[(et * 4 + 0) * 64 + lane];
                w1      = wfrag[(et * 4 + 1) * 64 + lane];
                w2f[et] = wfrag[(et * 4 + 2) * 64 + lane];
                w3f[et] = wfrag[(et * 4 + 3) * 64 + lane];
            } else {
                const int col = et * 16 + m16;
                #pragma unroll
                for (int j = 0; j < 8; ++j) {
                    const int k0 = quad * 8 + j;
                    if constexpr (FMODE == 0) {
                        w0[j]      = (short)((const unsigned short*)att_W1)[k0 * D_SZ + col];
                        w1[j]      = (short)((const unsigned short*)att_W1)[(k0 + 32) * D_SZ + col];
                        w2f[et][j] = (short)((const unsigned short*)att_W2)[k0 * D_SZ + col];
                        w3f[et][j] = (short)((const unsigned short*)att_W2)[(k0 + 32) * D_SZ + col];
                    } else {
                        w0[j]      = (short)f2bfbits(((const float*)att_W1)[k0 * D_SZ + col]);
                        w1[j]      = (short)f2bfbits(((const float*)att_W1)[(k0 + 32) * D_SZ + col]);
                        w2f[et][j] = (short)f2bfbits(((const float*)att_W2)[k0 * D_SZ + col]);
                        w3f[et][j] = (short)f2bfbits(((const float*)att_W2)[(k0 + 32) * D_SZ + col]);
                    }
                }
            }
            f32x4 z = {0.f, 0.f, 0.f, 0.f};
            z = __builtin_amdgcn_mfma_f32_16x16x32_bf16(a0, w0, z, 0, 0, 0);
            z = __builtin_amdgcn_mfma_f32_16x16x32_bf16(a1, w1, z, 0, 0, 0);
            accN[et] = z;
            ve[et]   = LD<FMODE>(att_v, et * 16 + m16);
        }

        #pragma unroll
        for (int mt = 0; mt < 4; ++mt) {
            const unsigned short* Ar = sm.A + (r * 65 + mt * 16 + m16) * ARS + quad * 8;
            const bf16x8 a2 = *(const bf16x8*)Ar;          // neigh k  0..31
            const bf16x8 a3 = *(const bf16x8*)(Ar + 32);   // neigh k 32..63
            float p0 = 0.f, p1 = 0.f, p2 = 0.f, p3 = 0.f;
            #pragma unroll
            for (int et = 0; et < 4; ++et) {
                f32x4 acc = __builtin_amdgcn_mfma_f32_16x16x32_bf16(a2, w2f[et], accN[et], 0, 0, 0);
                acc       = __builtin_amdgcn_mfma_f32_16x16x32_bf16(a3, w3f[et], acc,      0, 0, 0);
                p0 = fmaf(tanh_fast(acc[0]), ve[et], p0);
                p1 = fmaf(tanh_fast(acc[1]), ve[et], p1);
                p2 = fmaf(tanh_fast(acc[2]), ve[et], p2);
                p3 = fmaf(tanh_fast(acc[3]), ve[et], p3);
            }
            p0 = dpp_add<0xB1>(p0); p0 = dpp_add<0x4E>(p0); p0 = dpp_add<0x124>(p0); p0 = dpp_add<0x128>(p0);
            p1 = dpp_add<0xB1>(p1); p1 = dpp_add<0x4E>(p1); p1 = dpp_add<0x124>(p1); p1 = dpp_add<0x128>(p1);
            p2 = dpp_add<0xB1>(p2); p2 = dpp_add<0x4E>(p2); p2 = dpp_add<0x124>(p2); p2 = dpp_add<0x128>(p2);
            p3 = dpp_add<0xB1>(p3); p3 = dpp_add<0x4E>(p3); p3 = dpp_add<0x124>(p3); p3 = dpp_add<0x128>(p3);
            if (m16 == 0) {
                sm.att[r][mt * 16 + quad * 4 + 0] = p0;
                sm.att[r][mt * 16 + quad * 4 + 1] = p1;
                sm.att[r][mt * 16 + quad * 4 + 2] = p2;
                sm.att[r][mt * 16 + quad * 4 + 3] = p3;
            }
        }
    }

    // ---- Phase 3: scores -> wn; feature_hist -> comb (wave-private) ----
    {
        const int r   = wv;
        const int idx = (b0 + r) * N_SZ + lane;
        const float dt = LD<FMODE>(dt_neigh, idx);
        const float ts = 1.0f / fmaf(2.0f, dt, 1.0f);   // Decayer(2,'rev')
        const float lr = ts >= 0.0f ? ts : 0.01f * ts;  // leaky_relu
        const float m  = mval(neigh_mask, idx, mmode);
        float cnt = m;
        #pragma unroll
        for (int off = 32; off > 0; off >>= 1) cnt += __shfl_down(cnt, off, 64);
        cnt = __shfl(cnt, 0, 64);
        sm.wn[r][lane] = m * lr * sm.att[r][lane] / fmaxf(cnt, 1.0f);

        if constexpr (FMODE == 0) {
            const unsigned u = ((const unsigned*)feature_hist)[(b0 + r) * 64 + lane];
            *(unsigned*)(sm.comb + r * CRS + 2 * D_SZ + 2 * lane) = u;
        } else {
            const float* fh = (const float*)feature_hist + (b0 + r) * 2 * D_SZ + 2 * lane;
            *(unsigned*)(sm.comb + r * CRS + 2 * D_SZ + 2 * lane) = pack2bf(fh[0], fh[1]);
        }
    }

    // ---- Phase 4: neigh_agg (wave-private; lane = d) ----
    {
        const int r = wv;
        float agg = 0.0f;
        #pragma unroll
        for (int n = 0; n < N_SZ; ++n) {
            const float w = sm.wn[r][n];                                  // LDS broadcast
            agg = fmaf(w, bits2f(sm.A[(r * 65 + n) * ARS + lane]), agg);  // 2-way, free
        }
        sm.comb[r * CRS + D_SZ + lane] = (unsigned short)f2bfbits(agg);
    }
    __syncthreads();

    // ---- Phase 5: GEMV via MFMA. A rows = comb[m16&3] (duplicated), N=128 h, K=256 ----
    {
        #pragma unroll
        for (int t2 = 0; t2 < 2; ++t2) {
            const int nt = wv * 2 + t2;
            f32x4 c = {0.f, 0.f, 0.f, 0.f};
            #pragma unroll
            for (int ks = 0; ks < 8; ++ks) {
                const bf16x8 af = *(const bf16x8*)(sm.comb + (m16 & 3) * CRS + ks * 32 + quad * 8);
                bf16x8 bw;
                if constexpr (FMODE == 0) {
                    bw = *(const bf16x8*)((const unsigned short*)weight
                            + (nt * 16 + m16) * (4 * D_SZ) + ks * 32 + quad * 8);
                } else {
                    const float* wr = (const float*)weight
                            + (nt * 16 + m16) * (4 * D_SZ) + ks * 32 + quad * 8;
                    #pragma unroll
                    for (int j = 0; j < 8; ++j) bw[j] = (short)f2bfbits(wr[j]);
                }
                c = __builtin_amdgcn_mfma_f32_16x16x32_bf16(af, bw, c, 0, 0, 0);
            }
            if (quad == 0) {   // C rows 0..3 = quad 0, regs 0..3; col = m16
                #pragma unroll
                for (int rr = 0; rr < 4; ++rr) {
                    const float v = fmaxf(c[rr], 0.0f);
                    if constexpr (FMODE == 0)
                        ((__hip_bfloat16*)out)[(b0 + rr) * H_SZ + nt * 16 + m16] = __float2bfloat16(v);
                    else
                        ((float*)out)[(b0 + rr) * H_SZ + nt * 16 + m16] = v;
                }
            }
        }
    }
}

template<bool USE_WS>
__global__ __launch_bounds__(256, 4) void fused_model_kernel(
    const void* dt_node, const void* deg_node, const void* cc_node,
    const void* dt_neigh, const void* deg_neigh, const void* cc_neigh,
    const void* neigh_mask, const void* feature_hist,
    const void* t2v_w, const void* t2v_b, const void* node_w, const void* node_b,
    const void* att_W1, const void* att_W2, const void* att_v,
    const void* weight, void* out, const void* ws)
{
    __shared__ Smem sm;
    const int b0  = blockIdx.x * R_PB;
    const int tid = threadIdx.x;

    // wave-uniform dtype detection on head bytes (no LDS, no barrier)
    const int fmode = __builtin_amdgcn_readfirstlane(detect_f32(dt_node));
    const int mmode = __builtin_amdgcn_readfirstlane(detect_mask_mode(neigh_mask));

    if (fmode == 0)
        body<0, USE_WS>(sm, dt_node, deg_node, cc_node, dt_neigh, deg_neigh, cc_neigh,
                        neigh_mask, feature_hist, t2v_w, t2v_b, node_w, node_b,
                        att_W1, att_W2, att_v, weight, out, ws, mmode, b0, tid);
    else
        body<1, USE_WS>(sm, dt_node, deg_node, cc_node, dt_neigh, deg_neigh, cc_neigh,
                        neigh_mask, feature_hist, t2v_w, t2v_b, node_w, node_b,
                        att_W1, att_W2, att_v, weight, out, ws, mmode, b0, tid);
}

extern "C" void kernel_launch(void* const* d_in, const int* in_sizes, int n_in,
                              void* d_out, int out_size, void* d_ws, size_t ws_size,
                              hipStream_t stream) {
    const bool use_ws = (ws_size >= 16384) && (d_ws != nullptr);
    if (use_ws) {
        prep_kernel<<<4, 256, 0, stream>>>(d_in[0], d_in[12], d_in[13], d_ws);
        fused_model_kernel<true><<<B_SZ / R_PB, 256, 0, stream>>>(
            d_in[0], d_in[1], d_in[2], d_in[3], d_in[4], d_in[5], d_in[6], d_in[7],
            d_in[8], d_in[9], d_in[10], d_in[11], d_in[12], d_in[13], d_in[14], d_in[15],
            d_out, d_ws);
    } else {
        fused_model_kernel<false><<<B_SZ / R_PB, 256, 0, stream>>>(
            d_in[0], d_in[1], d_in[2], d_in[3], d_in[4], d_in[5], d_in[6], d_in[7],
            d_in[8], d_in[9], d_in[10], d_in[11], d_in[12], d_in[13], d_in[14], d_in[15],
            d_out, d_ws);
    }
}